// Round 1
// baseline (315.941 us; speedup 1.0000x reference)
//
#include <hip/hip_runtime.h>
#include <math.h>
#include <stdint.h>

#define B_ 64
#define J_ 512
#define D_ 1024

typedef __attribute__((ext_vector_type(8))) short short8;
typedef __attribute__((ext_vector_type(4))) float f32x4;

#define GLOBAL_AS __attribute__((address_space(1)))
#define LDS_AS    __attribute__((address_space(3)))

__device__ __forceinline__ void async16(const void* g, void* l) {
    __builtin_amdgcn_global_load_lds((const GLOBAL_AS uint32_t*)g,
                                     (LDS_AS uint32_t*)l, 16, 0, 0);
}

// tanh(x) = 1 - 2/(1+e^{2x}); saturates correctly for |x| large.
__device__ __forceinline__ float fast_tanh(float x) {
    return 1.0f - 2.0f / (1.0f + __expf(2.0f * x));
}

// fp32 -> bf16 round-to-nearest-even
__device__ __forceinline__ unsigned short f2bf(float f) {
    uint32_t u = __builtin_bit_cast(uint32_t, f);
    u += 0x7fffu + ((u >> 16) & 1u);
    return (unsigned short)(u >> 16);
}

__device__ __forceinline__ uint32_t pk2(float a, float b) {
    return (uint32_t)f2bf(a) | ((uint32_t)f2bf(b) << 16);
}

// ---------------------------------------------------------------------------
// W1[k][n] fp32 -> W1t[n][k] bf16 (so B-operand frags are contiguous in k)
// ---------------------------------------------------------------------------
__global__ __launch_bounds__(256) void transpose_cast_w1(const float* __restrict__ W1,
                                                         unsigned short* __restrict__ W1t) {
    __shared__ float t[32][33];
    const int n = blockIdx.x * 32 + threadIdx.x;
    for (int i = threadIdx.y; i < 32; i += 8)
        t[i][threadIdx.x] = W1[(size_t)(blockIdx.y * 32 + i) * D_ + n];
    __syncthreads();
    const int k = blockIdx.y * 32 + threadIdx.x;
    for (int i = threadIdx.y; i < 32; i += 8)
        W1t[(size_t)(blockIdx.x * 32 + i) * D_ + k] = f2bf(t[threadIdx.x][i]);
}

// ---------------------------------------------------------------------------
// Fused gemm+score kernel. Block tile: 64(M) x 256(N), BK=64, 8 waves (1x8 N).
// A is reg-staged from f32 x (cast fused in, overlapped with MFMA phase);
// B is double-buffered via global_load_lds with cross-barrier prefetch.
// Full-N sweep per block -> per-row pv completes in-block; fused sigmoid/mask
// and unnormalized pooling (normalization commutes to finalize).
// ---------------------------------------------------------------------------
__global__ __launch_bounds__(512, 4) void gemm_score_kernel(
    const float* __restrict__ x, const unsigned short* __restrict__ W1t,
    const float* __restrict__ b1, const float* __restrict__ W2,
    const float* __restrict__ b2, const float* __restrict__ mask,
    float* __restrict__ val_ws, float* __restrict__ pooled)
{
    __shared__ __align__(16) unsigned short ldsA[64 * 64];        // [m][k], k-chunk swizzled
    __shared__ __align__(16) unsigned short ldsB[2 * 256 * 64];   // dbuf [n][k], k-chunk swizzled
    __shared__ float pv_part[8][64];
    __shared__ float vrow[64];

    const int tid  = threadIdx.x;
    const int wave = tid >> 6;
    const int l    = tid & 63;
    const int wn   = wave;            // wave grid 1(M) x 8(N)
    const int l15  = l & 15;
    const int kgrp = l >> 4;
    const int l7   = l & 7;
    const int r0   = blockIdx.x * 64; // 64 rows per block, within one batch
    const int bb   = r0 >> 9;

    // --- A staging: thread owns row=tid>>3, LDS chunk c=tid&7 (holds global
    //     chunk c^(row&7)); source is f32 x, converted in-register ---
    const int arow = tid >> 3;
    const int achv = ((tid & 7) ^ (arow & 7)) << 3;   // swizzled k-chunk (elements)
    const float* gAf = x + (size_t)(r0 + arow) * D_ + achv;
    unsigned short* lA = ldsA + tid * 8;              // = row*64 + c*8, 16B/thread

    // --- B staging via global_load_lds (wave-uniform base + lane*16) ---
    const unsigned short* gB[4];
    unsigned short* lB[4];
    #pragma unroll
    for (int t = 0; t < 4; ++t) {
        const int f = tid + t * 512;
        const int row = f >> 3;
        const int ch = ((f & 7) ^ (row & 7)) << 3;
        gB[t] = W1t + (size_t)row * D_ + ch;
        lB[t] = ldsB + t * 4096 + (wave << 9);
    }

    // --- fragment LDS offsets (ushort units), swizzle-consistent ---
    int aoff[4][2], boff[2][2];
    #pragma unroll
    for (int mi = 0; mi < 4; ++mi)
        #pragma unroll
        for (int ks = 0; ks < 2; ++ks)
            aoff[mi][ks] = (mi * 16 + l15) * 64 + (((ks * 4 + kgrp) ^ l7) << 3);
    #pragma unroll
    for (int ni = 0; ni < 2; ++ni)
        #pragma unroll
        for (int ks = 0; ks < 2; ++ks)
            boff[ni][ks] = (wn * 32 + ni * 16 + l15) * 64 + (((ks * 4 + kgrp) ^ l7) << 3);

    float pv[4][4];
    #pragma unroll
    for (int mi = 0; mi < 4; ++mi)
        #pragma unroll
        for (int r = 0; r < 4; ++r) pv[mi][r] = 0.f;

    f32x4 acc[4][2];
    #pragma unroll
    for (int mi = 0; mi < 4; ++mi)
        #pragma unroll
        for (int ni = 0; ni < 2; ++ni)
            acc[mi][ni] = (f32x4){0.f, 0.f, 0.f, 0.f};

    // --- prologue: A[0] -> regs + cvt; B[0] async into buffer 0 ---
    float4 fA0 = *reinterpret_cast<const float4*>(gAf);
    float4 fA1 = *reinterpret_cast<const float4*>(gAf + 4);
    #pragma unroll
    for (int t = 0; t < 4; ++t) async16(gB[t], lB[t]);
    uint32_t apk0 = pk2(fA0.x, fA0.y);
    uint32_t apk1 = pk2(fA0.z, fA0.w);
    uint32_t apk2 = pk2(fA1.x, fA1.y);
    uint32_t apk3 = pk2(fA1.z, fA1.w);

    // 64 flat iterations: n0 = it>>4, k0 = (it&15)*64
    for (int it = 0; it < 64; ++it) {
        const int cur = it & 1;

        // X barrier: full drain (vmcnt(0) -> B[it] landed) + WAR guard for
        // ldsA and ldsB[cur^1] which we are about to overwrite.
        __syncthreads();

        // publish A[it] (16B ds_write from regs, converted last iteration)
        *reinterpret_cast<uint4*>(lA) = (uint4){apk0, apk1, apk2, apk3};

        // issue next-step prefetch: A[it+1] f32 -> regs, B[it+1] -> ldsB[cur^1]
        if (it < 63) {
            const int nit  = it + 1;
            const int nk0  = (nit & 15) << 6;
            const size_t nbofs = (size_t)(nit >> 4) * 256 * D_ + nk0;
            fA0 = *reinterpret_cast<const float4*>(gAf + nk0);
            fA1 = *reinterpret_cast<const float4*>(gAf + nk0 + 4);
            const int nbuf = (cur ^ 1) << 14;
            #pragma unroll
            for (int t = 0; t < 4; ++t) async16(gB[t] + nbofs, lB[t] + nbuf);
        }

        // Y barrier: publish the A ds_write; B[it+1] stays in flight across it.
        asm volatile("s_waitcnt lgkmcnt(0)" ::: "memory");
        __builtin_amdgcn_s_barrier();
        asm volatile("" ::: "memory");

        const int bo = cur << 14;   // dbuf offset in ushorts
        #pragma unroll
        for (int ks = 0; ks < 2; ++ks) {
            const short8 a0 = *reinterpret_cast<const short8*>(ldsA + aoff[0][ks]);
            const short8 a1 = *reinterpret_cast<const short8*>(ldsA + aoff[1][ks]);
            const short8 a2 = *reinterpret_cast<const short8*>(ldsA + aoff[2][ks]);
            const short8 a3 = *reinterpret_cast<const short8*>(ldsA + aoff[3][ks]);
            const short8 b0 = *reinterpret_cast<const short8*>(ldsB + bo + boff[0][ks]);
            const short8 b1f = *reinterpret_cast<const short8*>(ldsB + bo + boff[1][ks]);
            acc[0][0] = __builtin_amdgcn_mfma_f32_16x16x32_bf16(a0, b0,  acc[0][0], 0, 0, 0);
            acc[1][0] = __builtin_amdgcn_mfma_f32_16x16x32_bf16(a1, b0,  acc[1][0], 0, 0, 0);
            acc[2][0] = __builtin_amdgcn_mfma_f32_16x16x32_bf16(a2, b0,  acc[2][0], 0, 0, 0);
            acc[3][0] = __builtin_amdgcn_mfma_f32_16x16x32_bf16(a3, b0,  acc[3][0], 0, 0, 0);
            acc[0][1] = __builtin_amdgcn_mfma_f32_16x16x32_bf16(a0, b1f, acc[0][1], 0, 0, 0);
            acc[1][1] = __builtin_amdgcn_mfma_f32_16x16x32_bf16(a1, b1f, acc[1][1], 0, 0, 0);
            acc[2][1] = __builtin_amdgcn_mfma_f32_16x16x32_bf16(a2, b1f, acc[2][1], 0, 0, 0);
            acc[3][1] = __builtin_amdgcn_mfma_f32_16x16x32_bf16(a3, b1f, acc[3][1], 0, 0, 0);
        }

        // convert prefetched A[it+1] during/after the MFMA phase (off barrier path)
        if (it < 63) {
            apk0 = pk2(fA0.x, fA0.y);
            apk1 = pk2(fA0.z, fA0.w);
            apk2 = pk2(fA1.x, fA1.y);
            apk3 = pk2(fA1.z, fA1.w);
        }

        // n0-tile boundary: fold this 256-col tile of h into pv, reset acc
        if ((it & 15) == 15) {
            const int n0 = it >> 4;
            #pragma unroll
            for (int ni = 0; ni < 2; ++ni) {
                const int col = n0 * 256 + wn * 32 + ni * 16 + l15;
                const float b1v = b1[col];
                const float w2v = W2[col];
                #pragma unroll
                for (int mi = 0; mi < 4; ++mi)
                    #pragma unroll
                    for (int r = 0; r < 4; ++r) {
                        const float h = fast_tanh(acc[mi][ni][r] + b1v);
                        pv[mi][r] = fmaf(h, w2v, pv[mi][r]);
                        acc[mi][ni][r] = 0.f;
                    }
            }
        }
    }

    // reduce pv over the 16 col-lanes (C/D layout: row = kgrp*4+r, col = l15)
    #pragma unroll
    for (int mi = 0; mi < 4; ++mi)
        #pragma unroll
        for (int r = 0; r < 4; ++r) {
            float s = pv[mi][r];
            s += __shfl_xor(s, 1);
            s += __shfl_xor(s, 2);
            s += __shfl_xor(s, 4);
            s += __shfl_xor(s, 8);
            if (l15 == 0) pv_part[wn][mi * 16 + kgrp * 4 + r] = s;
        }
    __syncthreads();
    if (tid < 64) {
        float s = b2[0];
        #pragma unroll
        for (int w = 0; w < 8; ++w) s += pv_part[w][tid];
        const float sg = 1.0f / (1.0f + __expf(-s));
        const float v = sg * mask[r0 + tid];
        val_ws[r0 + tid] = v;
        vrow[tid] = v;
    }
    __syncthreads();

    // unnormalized pooled: pooled[bb][k] += sum_rows x[r][k]*val[r] (x f32, L3-hot)
    const int kc = tid << 1;
    float a0 = 0.f, a1 = 0.f;
    for (int row = 0; row < 64; ++row) {
        const float v = vrow[row];
        const float2 xv = *reinterpret_cast<const float2*>(
            x + (size_t)(r0 + row) * D_ + kc);
        a0 = fmaf(xv.x, v, a0);
        a1 = fmaf(xv.y, v, a1);
    }
    atomicAdd(&pooled[bb * D_ + kc], a0);
    atomicAdd(&pooled[bb * D_ + kc + 1], a1);
}

// ---------------------------------------------------------------------------
// Fallback fp32 path (used only if ws too small)
// ---------------------------------------------------------------------------
#define MT 64
#define KT 32
#define PAD 68

__global__ __launch_bounds__(256) void score_kernel_fp32(
    const float* __restrict__ x, const float* __restrict__ mask,
    const float* __restrict__ W1, const float* __restrict__ b1,
    const float* __restrict__ W2, const float* __restrict__ b2,
    float* __restrict__ val_ws, float* __restrict__ pooled)
{
    __shared__ float As[KT][PAD];
    __shared__ float Bs[KT][PAD];
    __shared__ float red[MT][17];
    __shared__ float vrow[MT];

    const int tid = threadIdx.x;
    const int tx = tid & 15;
    const int ty = tid >> 4;
    const int r0 = blockIdx.x * MT;
    const int b  = r0 >> 9;

    float pv[4] = {0.f, 0.f, 0.f, 0.f};

    for (int n0 = 0; n0 < D_; n0 += 64) {
        float acc[4][4];
        #pragma unroll
        for (int i = 0; i < 4; ++i)
            #pragma unroll
            for (int j = 0; j < 4; ++j) acc[i][j] = 0.f;

        for (int k0 = 0; k0 < D_; k0 += KT) {
            #pragma unroll
            for (int ll = 0; ll < 2; ++ll) {
                const int f   = tid + ll * 256;
                const int row = f >> 3;
                const int k4  = (f & 7) << 2;
                const float4 xv = *reinterpret_cast<const float4*>(
                    &x[(size_t)(r0 + row) * D_ + k0 + k4]);
                As[k4 + 0][row] = xv.x;
                As[k4 + 1][row] = xv.y;
                As[k4 + 2][row] = xv.z;
                As[k4 + 3][row] = xv.w;
            }
            #pragma unroll
            for (int ll = 0; ll < 2; ++ll) {
                const int f  = tid + ll * 256;
                const int k  = f >> 4;
                const int n4 = (f & 15) << 2;
                const float4 wv = *reinterpret_cast<const float4*>(
                    &W1[(size_t)(k0 + k) * D_ + n0 + n4]);
                *reinterpret_cast<float4*>(&Bs[k][n4]) = wv;
            }
            __syncthreads();
            #pragma unroll
            for (int kk = 0; kk < KT; ++kk) {
                const float4 a4 = *reinterpret_cast<const float4*>(&As[kk][ty << 2]);
                const float4 b4 = *reinterpret_cast<const float4*>(&Bs[kk][tx << 2]);
                const float av[4] = {a4.x, a4.y, a4.z, a4.w};
                const float bv[4] = {b4.x, b4.y, b4.z, b4.w};
                #pragma unroll
                for (int i = 0; i < 4; ++i)
                    #pragma unroll
                    for (int j = 0; j < 4; ++j)
                        acc[i][j] = fmaf(av[i], bv[j], acc[i][j]);
            }
            __syncthreads();
        }
        #pragma unroll
        for (int j = 0; j < 4; ++j) {
            const int col = n0 + (tx << 2) + j;
            const float b1v = b1[col];
            const float w2v = W2[col];
            #pragma unroll
            for (int i = 0; i < 4; ++i) {
                const float h = fast_tanh(acc[i][j] + b1v);
                pv[i] = fmaf(h, w2v, pv[i]);
            }
        }
    }

    #pragma unroll
    for (int i = 0; i < 4; ++i) red[(ty << 2) + i][tx] = pv[i];
    __syncthreads();

    if (tid < MT) {
        float s = 0.f;
        #pragma unroll
        for (int t = 0; t < 16; ++t) s += red[tid][t];
        const float z  = s + b2[0];
        const float sg = 1.0f / (1.0f + __expf(-z));
        const float v  = sg * mask[r0 + tid];
        val_ws[r0 + tid] = v;
        vrow[tid] = v;
    }
    __syncthreads();

    const int k = tid << 2;
    float a0 = 0.f, a1 = 0.f, a2 = 0.f, a3 = 0.f;
    for (int row = 0; row < MT; ++row) {
        const float v = vrow[row];
        const float4 xv = *reinterpret_cast<const float4*>(
            &x[(size_t)(r0 + row) * D_ + k]);
        a0 = fmaf(xv.x, v, a0);
        a1 = fmaf(xv.y, v, a1);
        a2 = fmaf(xv.z, v, a2);
        a3 = fmaf(xv.w, v, a3);
    }
    float* pb = &pooled[b * D_ + k];
    atomicAdd(pb + 0, a0);
    atomicAdd(pb + 1, a1);
    atomicAdd(pb + 2, a2);
    atomicAdd(pb + 3, a3);
}

__global__ __launch_bounds__(256) void finalize_kernel(
    const float* __restrict__ val_ws, const float* __restrict__ pooled,
    const float* __restrict__ W3, const float* __restrict__ b3,
    float* __restrict__ out)
{
    __shared__ float sred[256];
    const int b = blockIdx.x;
    const int tid = threadIdx.x;

    const float v0 = val_ws[b * J_ + tid];
    const float v1 = val_ws[b * J_ + 256 + tid];
    sred[tid] = v0 + v1;
    __syncthreads();
    for (int s = 128; s > 0; s >>= 1) {
        if (tid < s) sred[tid] += sred[tid + s];
        __syncthreads();
    }
    const float inv = 1.0f / sred[0];

    out[192 + b * J_ + tid]       = v0 * inv;
    out[192 + b * J_ + 256 + tid] = v1 * inv;

    const int k = tid << 2;
    float acc3[3] = {0.f, 0.f, 0.f};
    #pragma unroll
    for (int c = 0; c < 4; ++c) {
        const float p = pooled[b * D_ + k + c] * inv;
        acc3[0] = fmaf(p, W3[(k + c) * 3 + 0], acc3[0]);
        acc3[1] = fmaf(p, W3[(k + c) * 3 + 1], acc3[1]);
        acc3[2] = fmaf(p, W3[(k + c) * 3 + 2], acc3[2]);
    }
    for (int o = 0; o < 3; ++o) {
        __syncthreads();
        sred[tid] = acc3[o];
        __syncthreads();
        for (int s = 128; s > 0; s >>= 1) {
            if (tid < s) sred[tid] += sred[tid + s];
            __syncthreads();
        }
        if (tid == 0) out[b * 3 + o] = sred[0] + b3[o];
    }
}

extern "C" void kernel_launch(void* const* d_in, const int* in_sizes, int n_in,
                              void* d_out, int out_size, void* d_ws, size_t ws_size,
                              hipStream_t stream) {
    const float* x    = (const float*)d_in[0];
    const float* mask = (const float*)d_in[1];
    const float* W1   = (const float*)d_in[2];
    const float* b1   = (const float*)d_in[3];
    const float* W2   = (const float*)d_in[4];
    const float* b2   = (const float*)d_in[5];
    const float* W3   = (const float*)d_in[6];
    const float* b3   = (const float*)d_in[7];
    float* out = (float*)d_out;

    const size_t W1T_BYTES  = (size_t)D_ * D_ * 2;        //  2,097,152
    const size_t VAL_BYTES  = (size_t)B_ * J_ * 4;        //    131,072
    const size_t POOL_BYTES = (size_t)B_ * D_ * 4;        //    262,144
    const size_t NEED = W1T_BYTES + VAL_BYTES + POOL_BYTES;

    if (ws_size >= NEED) {
        unsigned short* W1t = (unsigned short*)d_ws;
        float* val_ws = (float*)((char*)d_ws + W1T_BYTES);
        float* pooled = (float*)((char*)d_ws + W1T_BYTES + VAL_BYTES);

        hipMemsetAsync(pooled, 0, POOL_BYTES, stream);
        transpose_cast_w1<<<dim3(32, 32), dim3(32, 8), 0, stream>>>(W1, W1t);
        gemm_score_kernel<<<512, 512, 0, stream>>>(x, W1t, b1, W2, b2, mask,
                                                   val_ws, pooled);
        finalize_kernel<<<B_, 256, 0, stream>>>(val_ws, pooled, W3, b3, out);
    } else {
        float* val_ws = (float*)d_ws;
        float* pooled = val_ws + B_ * J_;
        hipMemsetAsync(pooled, 0, POOL_BYTES, stream);
        score_kernel_fp32<<<(B_ * J_) / MT, 256, 0, stream>>>(
            x, mask, W1, b1, W2, b2, val_ws, pooled);
        finalize_kernel<<<B_, 256, 0, stream>>>(val_ws, pooled, W3, b3, out);
    }
}